// Round 1
// baseline (256.871 us; speedup 1.0000x reference)
//
#include <hip/hip_runtime.h>

#define LOG2E 1.44269504088896340736f

// e^x via v_exp_f32 (2^x)
__device__ __forceinline__ float fast_exp(float x) {
    return __builtin_amdgcn_exp2f(x * LOG2E);
}
// sigmoid(x) = 1 / (1 + e^-x); e^-x -> +inf gives rcp(inf)=0: safe, no NaN
__device__ __forceinline__ float fast_sigmoid(float x) {
    return __builtin_amdgcn_rcpf(1.0f + __builtin_amdgcn_exp2f(-LOG2E * x));
}
// tanh(x) = (1 - t) / (1 + t), t = e^{-2x}; clamp to avoid t=inf -> NaN
__device__ __forceinline__ float fast_tanh(float x) {
    float xx = fminf(fmaxf(x, -30.0f), 30.0f);
    float t = __builtin_amdgcn_exp2f(-2.0f * LOG2E * xx);
    return (1.0f - t) * __builtin_amdgcn_rcpf(1.0f + t);
}

// LSTM cell with h0=c0=0: gates = x@W_ih.T + b_ih + b_hh; PyTorch order i,f,g,o.
// f gate is dead (f*c0 == 0) -> compute only i (rows 0..11), g (24..35), o (36..47).
// c = sigmoid(i)*tanh(g); h = sigmoid(o)*tanh(c)
template <int K>
__device__ __forceinline__ void lstm_cell(const float* __restrict__ W,
                                          const float* __restrict__ bi,
                                          const float* __restrict__ bh,
                                          const float* xin, float* h) {
#pragma unroll
    for (int j = 0; j < 12; ++j) {
        float gi = bi[j]      + bh[j];
        float gg = bi[24 + j] + bh[24 + j];
        float go = bi[36 + j] + bh[36 + j];
#pragma unroll
        for (int k = 0; k < K; ++k) {
            float xk = xin[k];
            gi = fmaf(W[j * K + k],        xk, gi);
            gg = fmaf(W[(24 + j) * K + k], xk, gg);
            go = fmaf(W[(36 + j) * K + k], xk, go);
        }
        float c = fast_sigmoid(gi) * fast_tanh(gg);
        h[j] = fast_sigmoid(go) * fast_tanh(c);
    }
}

__global__ __launch_bounds__(256) void dynnet_kernel(
    const float* __restrict__ x,
    const float* __restrict__ Wih1, const float* __restrict__ bih1, const float* __restrict__ bhh1,
    const float* __restrict__ Wih2, const float* __restrict__ bih2, const float* __restrict__ bhh2,
    const float* __restrict__ Wihm, const float* __restrict__ bihm, const float* __restrict__ bhhm,
    const float* __restrict__ Wihd, const float* __restrict__ bihd, const float* __restrict__ bhhd,
    float* __restrict__ out, int nrows)
{
    int row = blockIdx.x * blockDim.x + threadIdx.x;
    if (row >= nrows) return;

    // x[row][0..15]: 64B, float4-aligned, coalesced across the wave via L1
    float xin[16];
    const float4* xv = reinterpret_cast<const float4*>(x + (size_t)row * 16);
#pragma unroll
    for (int i = 0; i < 4; ++i) {
        float4 v = xv[i];
        xin[4 * i + 0] = v.x; xin[4 * i + 1] = v.y;
        xin[4 * i + 2] = v.z; xin[4 * i + 3] = v.w;
    }

    float h1[12], h2[12], hm[12], hd[12];

    // cell 1 -> relu
    lstm_cell<16>(Wih1, bih1, bhh1, xin, h1);
#pragma unroll
    for (int j = 0; j < 12; ++j) h1[j] = fmaxf(h1[j], 0.0f);

    // cell 2 -> selu
    lstm_cell<12>(Wih2, bih2, bhh2, h1, h2);
#pragma unroll
    for (int j = 0; j < 12; ++j) {
        float v = h2[j];
        float e = 1.6732632423543772f * (fast_exp(v) - 1.0f);
        h2[j] = 1.0507009873554805f * (v > 0.0f ? v : e);
    }

    // heads m, d -> tanh
    lstm_cell<12>(Wihm, bihm, bhhm, h2, hm);
    lstm_cell<12>(Wihd, bihd, bhhd, h2, hd);

    float mo[12], dvo[12];
#pragma unroll
    for (int j = 0; j < 12; ++j) {
        mo[j]  = fast_tanh(hm[j]);
        dvo[j] = fast_tanh(hd[j]);
    }

    // out = concat([m, dv], axis=0): m at row*12, dv at (nrows+row)*12.
    // 48B per row, 16B-aligned -> 3x float4 each.
    float4* om = reinterpret_cast<float4*>(out + (size_t)row * 12);
    float4* od = reinterpret_cast<float4*>(out + ((size_t)nrows + row) * 12);
    om[0] = make_float4(mo[0], mo[1], mo[2],  mo[3]);
    om[1] = make_float4(mo[4], mo[5], mo[6],  mo[7]);
    om[2] = make_float4(mo[8], mo[9], mo[10], mo[11]);
    od[0] = make_float4(dvo[0], dvo[1], dvo[2],  dvo[3]);
    od[1] = make_float4(dvo[4], dvo[5], dvo[6],  dvo[7]);
    od[2] = make_float4(dvo[8], dvo[9], dvo[10], dvo[11]);
}

extern "C" void kernel_launch(void* const* d_in, const int* in_sizes, int n_in,
                              void* d_out, int out_size, void* d_ws, size_t ws_size,
                              hipStream_t stream) {
    const float* x    = (const float*)d_in[0];
    const float* Wih1 = (const float*)d_in[1];
    const float* bih1 = (const float*)d_in[2];
    const float* bhh1 = (const float*)d_in[3];
    const float* Wih2 = (const float*)d_in[4];
    const float* bih2 = (const float*)d_in[5];
    const float* bhh2 = (const float*)d_in[6];
    const float* Wihm = (const float*)d_in[7];
    const float* bihm = (const float*)d_in[8];
    const float* bhhm = (const float*)d_in[9];
    const float* Wihd = (const float*)d_in[10];
    const float* bihd = (const float*)d_in[11];
    const float* bhhd = (const float*)d_in[12];
    float* out = (float*)d_out;

    int nrows = in_sizes[0] / 16;  // B
    int block = 256;
    int grid  = (nrows + block - 1) / block;
    dynnet_kernel<<<grid, block, 0, stream>>>(
        x, Wih1, bih1, bhh1, Wih2, bih2, bhh2,
        Wihm, bihm, bhhm, Wihd, bihd, bhhd, out, nrows);
}

// Round 2
// 213.525 us; speedup vs baseline: 1.2030x; 1.2030x over previous
//
#include <hip/hip_runtime.h>

#define L2E 1.4426950408889634f   // log2(e)

typedef float v2f __attribute__((ext_vector_type(2)));

__device__ __forceinline__ v2f exp2v(v2f a) {
    v2f r; r.x = __builtin_amdgcn_exp2f(a.x); r.y = __builtin_amdgcn_exp2f(a.y); return r;
}
__device__ __forceinline__ v2f rcpv(v2f a) {
    v2f r; r.x = __builtin_amdgcn_rcpf(a.x); r.y = __builtin_amdgcn_rcpf(a.y); return r;
}
__device__ __forceinline__ v2f fmav(v2f a, v2f b, v2f c) {
    return __builtin_elementwise_fma(a, b, c);
}
// tanh via [5/4] Pade (continued fraction to level 9): exact to ~5e-8 for |x|<=1
__device__ __forceinline__ v2f tanh_pade(v2f xv) {
    v2f x2 = xv * xv;
    v2f num = xv * (945.0f + x2 * (105.0f + x2));
    v2f den = 945.0f + x2 * (420.0f + 15.0f * x2);
    return num * rcpv(den);
}

// ---------------------------------------------------------------------------
// Workspace layout (floats):
//   [0    .. 576)  cell1 W pairs  (3 gates x 6 jp x K=16 x 2)
//   [576  ..1008)  cell2 W pairs  (K=12)
//   [1008 ..1440)  cellm W pairs
//   [1440 ..1872)  celld W pairs
//   [1872 ..2016)  biases: 4 cells x 36 (pre-added b_ih+b_hh, prescaled)
// W pair index: ((jp*3 + g)*K + k)*2 + e ; source row = goff[g] + 2*jp + e
// Gate scales fold the exp2 arguments: i,o -> -log2e ; g -> -2*log2e
// so that exp2(acc) == e^{-gate} (i,o) and e^{-2*gate} (g). f gate is dead
// (c0=0) and never touched.
// ---------------------------------------------------------------------------
__global__ void prep_kernel(
    const float* __restrict__ W1, const float* __restrict__ bi1, const float* __restrict__ bh1,
    const float* __restrict__ W2, const float* __restrict__ bi2, const float* __restrict__ bh2,
    const float* __restrict__ Wm, const float* __restrict__ bim, const float* __restrict__ bhm,
    const float* __restrict__ Wd, const float* __restrict__ bid, const float* __restrict__ bhd,
    float* __restrict__ ws)
{
    const float* Ws[4]  = {W1, W2, Wm, Wd};
    const float* bis[4] = {bi1, bi2, bim, bid};
    const float* bhs[4] = {bh1, bh2, bhm, bhd};
    const int   Ks[4]   = {16, 12, 12, 12};
    const int   wOff[4] = {0, 576, 1008, 1440};
    const int   goff[3] = {0, 24, 36};
    const float gsc[3]  = {-L2E, -2.0f * L2E, -L2E};

    int tid = threadIdx.x + blockIdx.x * blockDim.x;
    int nth = blockDim.x * gridDim.x;
    for (int c = 0; c < 4; ++c) {
        int K = Ks[c];
        int n = 3 * 6 * K * 2;
        for (int t = tid; t < n; t += nth) {
            int e  = t & 1;
            int u  = t >> 1;
            int k  = u % K;
            int g  = (u / K) % 3;
            int jp = u / (3 * K);
            int row = goff[g] + 2 * jp + e;
            ws[wOff[c] + t] = gsc[g] * Ws[c][row * K + k];
        }
        for (int t = tid; t < 36; t += nth) {
            int e  = t & 1;
            int u  = t >> 1;
            int g  = u % 3;
            int jp = u / 3;
            int row = goff[g] + 2 * jp + e;
            ws[1872 + c * 36 + t] = gsc[g] * (bis[c][row] + bhs[c][row]);
        }
    }
}

// One LSTM cell (zero state), 6 j-pairs, packed-fp32 math.
// Accumulators arrive pre-scaled so exp2(acc) gives e^{-i}, e^{-2g}, e^{-o}.
//   sig(i)*tanh(g) = (1-tg) * rcp((1+ei)(1+tg))        [merged rcp]
//   h = sig(o)*tanh(c) = c*P(c^2) * rcp((1+eo)*Q(c^2)) [merged rcp + Pade]
template <int K>
__device__ __forceinline__ void cell_core(const float* __restrict__ wsW,
                                          const float* __restrict__ wsB,
                                          const v2f* xs, v2f h[6])
{
#pragma unroll
    for (int jp = 0; jp < 6; ++jp) {
        const v2f* w  = reinterpret_cast<const v2f*>(wsW) + jp * 3 * K;
        const v2f* bp = reinterpret_cast<const v2f*>(wsB) + jp * 3;
        v2f ai = bp[0], ag = bp[1], ao = bp[2];
#pragma unroll
        for (int k = 0; k < K; ++k) {
            ai = fmav(w[k],         xs[k], ai);
            ag = fmav(w[K + k],     xs[k], ag);
            ao = fmav(w[2 * K + k], xs[k], ao);
        }
        v2f ei = exp2v(ai);
        v2f tg = exp2v(ag);
        v2f eo = exp2v(ao);
        v2f r_ig = rcpv((1.0f + ei) * (1.0f + tg));
        v2f c    = (1.0f - tg) * r_ig;           // sig(i)*tanh(g), in (-1,1)
        v2f c2   = c * c;
        v2f num  = c * (945.0f + c2 * (105.0f + c2));
        v2f den  = 945.0f + c2 * (420.0f + 15.0f * c2);
        v2f r_o  = rcpv((1.0f + eo) * den);      // sig(o) merged with Pade den
        h[jp]    = num * r_o;                    // sig(o)*tanh(c), in (-1,1)
    }
}

__global__ __launch_bounds__(256) void dynnet_kernel(
    const float* __restrict__ x, const float* __restrict__ ws,
    float* __restrict__ out, int nrows)
{
    int row = blockIdx.x * blockDim.x + threadIdx.x;
    if (row >= nrows) return;

    const float* W1 = ws;
    const float* W2 = ws + 576;
    const float* Wm = ws + 1008;
    const float* Wd = ws + 1440;
    const float* B1 = ws + 1872;
    const float* B2 = ws + 1908;
    const float* Bm = ws + 1944;
    const float* Bd = ws + 1980;

    // x[row][0..15]: splat each element into a v2f for packed FMAs
    v2f xs[16];
    const float4* xv = reinterpret_cast<const float4*>(x + (size_t)row * 16);
#pragma unroll
    for (int i = 0; i < 4; ++i) {
        float4 v = xv[i];
        xs[4 * i + 0].x = xs[4 * i + 0].y = v.x;
        xs[4 * i + 1].x = xs[4 * i + 1].y = v.y;
        xs[4 * i + 2].x = xs[4 * i + 2].y = v.z;
        xs[4 * i + 3].x = xs[4 * i + 3].y = v.w;
    }

    v2f h[6];

    // cell 1 -> relu -> splat
    cell_core<16>(W1, B1, xs, h);
    v2f h1s[12];
#pragma unroll
    for (int jp = 0; jp < 6; ++jp) {
        v2f r = __builtin_elementwise_max(h[jp], (v2f)0.0f);
        h1s[2 * jp + 0].x = h1s[2 * jp + 0].y = r.x;
        h1s[2 * jp + 1].x = h1s[2 * jp + 1].y = r.y;
    }

    // cell 2 -> selu -> splat
    cell_core<12>(W2, B2, h1s, h);
    v2f h2s[12];
#pragma unroll
    for (int jp = 0; jp < 6; ++jp) {
        v2f v  = h[jp];                       // in (-1,1): e^v safe
        v2f ev = exp2v(v * L2E);
        v2f ng = fmav(ev, (v2f)1.7580993408473766f, (v2f)(-1.7580993408473766f)); // lambda*alpha*(e^v-1)
        v2f ps = v * 1.0507009873554805f;
        v2f s;
        s.x = v.x > 0.0f ? ps.x : ng.x;
        s.y = v.y > 0.0f ? ps.y : ng.y;
        h2s[2 * jp + 0].x = h2s[2 * jp + 0].y = s.x;
        h2s[2 * jp + 1].x = h2s[2 * jp + 1].y = s.y;
    }

    // heads m, d -> final tanh (bounded input -> Pade)
    v2f hm[6], hd[6];
    cell_core<12>(Wm, Bm, h2s, hm);
    cell_core<12>(Wd, Bd, h2s, hd);

    float mo[12], dvo[12];
#pragma unroll
    for (int jp = 0; jp < 6; ++jp) {
        v2f tm = tanh_pade(hm[jp]);
        v2f td = tanh_pade(hd[jp]);
        mo[2 * jp]  = tm.x; mo[2 * jp + 1]  = tm.y;
        dvo[2 * jp] = td.x; dvo[2 * jp + 1] = td.y;
    }

    // out = concat([m, dv], axis=0)
    float4* om = reinterpret_cast<float4*>(out + (size_t)row * 12);
    float4* od = reinterpret_cast<float4*>(out + ((size_t)nrows + row) * 12);
    om[0] = make_float4(mo[0], mo[1], mo[2],  mo[3]);
    om[1] = make_float4(mo[4], mo[5], mo[6],  mo[7]);
    om[2] = make_float4(mo[8], mo[9], mo[10], mo[11]);
    od[0] = make_float4(dvo[0], dvo[1], dvo[2],  dvo[3]);
    od[1] = make_float4(dvo[4], dvo[5], dvo[6],  dvo[7]);
    od[2] = make_float4(dvo[8], dvo[9], dvo[10], dvo[11]);
}

extern "C" void kernel_launch(void* const* d_in, const int* in_sizes, int n_in,
                              void* d_out, int out_size, void* d_ws, size_t ws_size,
                              hipStream_t stream) {
    const float* x    = (const float*)d_in[0];
    const float* Wih1 = (const float*)d_in[1];
    const float* bih1 = (const float*)d_in[2];
    const float* bhh1 = (const float*)d_in[3];
    const float* Wih2 = (const float*)d_in[4];
    const float* bih2 = (const float*)d_in[5];
    const float* bhh2 = (const float*)d_in[6];
    const float* Wihm = (const float*)d_in[7];
    const float* bihm = (const float*)d_in[8];
    const float* bhhm = (const float*)d_in[9];
    const float* Wihd = (const float*)d_in[10];
    const float* bihd = (const float*)d_in[11];
    const float* bhhd = (const float*)d_in[12];
    float* out = (float*)d_out;
    float* ws  = (float*)d_ws;   // needs 2016 floats = 8064 B

    prep_kernel<<<4, 256, 0, stream>>>(Wih1, bih1, bhh1, Wih2, bih2, bhh2,
                                       Wihm, bihm, bhhm, Wihd, bihd, bhhd, ws);

    int nrows = in_sizes[0] / 16;  // B
    int block = 256;
    int grid  = (nrows + block - 1) / block;
    dynnet_kernel<<<grid, block, 0, stream>>>(x, ws, out, nrows);
}